// Round 14
// baseline (144.384 us; speedup 1.0000x reference)
//
#include <hip/hip_runtime.h>

#define HW   50176      // 224*224
#define NPAR 4576       // KAN_PARAMS_NUM

typedef _Float16 half8 __attribute__((ext_vector_type(8)));
typedef __fp16 fp16x2 __attribute__((ext_vector_type(2)));
typedef __attribute__((ext_vector_type(4))) float f32x4;
typedef __attribute__((ext_vector_type(4))) int int4v;

__device__ __forceinline__ unsigned short f2h(float f) {
    union { _Float16 h; unsigned short u; } c; c.h = (_Float16)f; return c.u;
}
__device__ __forceinline__ float h2f(unsigned short u) {
    union { _Float16 h; unsigned short u; } c; c.u = u; return (float)c.h;
}
__device__ __forceinline__ int pkrtz(float lo, float hi) {
    union { fp16x2 h; int i; } c;
    c.h = __builtin_amdgcn_cvt_pkrtz(lo, hi);
    return c.i;
}

// ---------------------------------------------------------------------------
// Stage 1: w[m][n] = features[m][:] . fc_w[n][:] + fc_b[n]  via fp16 MFMA.
// Split-K across 4 waves + LDS reduction. 286 blocks (16 n each). (unchanged)
// ---------------------------------------------------------------------------
__global__ __launch_bounds__(256) void gemm_w(const float* __restrict__ feats,
                                              const float* __restrict__ fcw,
                                              const float* __restrict__ fcb,
                                              float* __restrict__ wout) {
    __shared__ float red[4][64][4];
    int tid = threadIdx.x, lane = tid & 63, wave = tid >> 6;
    int nn = lane & 15, quad = lane >> 4;
    int n = blockIdx.x * 16 + nn;
    const float* brow = fcw + (size_t)n * 1000;
    const float* arow = feats + nn * 1000;          // deref'd only if nn<8

    f32x4 acc = {0.f, 0.f, 0.f, 0.f};
#pragma unroll 4
    for (int s8 = 0; s8 < 8; s8++) {
        int kb = (wave * 8 + s8) * 32 + quad * 8;
        float4 a0 = {0,0,0,0}, a1 = {0,0,0,0}, b0 = {0,0,0,0}, b1 = {0,0,0,0};
        if (kb < 1000) {                            // 1000 % 8 == 0
            b0 = *(const float4*)(brow + kb);
            b1 = *(const float4*)(brow + kb + 4);
            if (nn < 8) {
                a0 = *(const float4*)(arow + kb);
                a1 = *(const float4*)(arow + kb + 4);
            }
        }
        float af[8] = {a0.x, a0.y, a0.z, a0.w, a1.x, a1.y, a1.z, a1.w};
        float bf[8] = {b0.x, b0.y, b0.z, b0.w, b1.x, b1.y, b1.z, b1.w};
        half8 ah, al, bh;
#pragma unroll
        for (int j = 0; j < 8; j++) {
            ah[j] = (_Float16)af[j];
            al[j] = (_Float16)(af[j] - (float)ah[j]);
            bh[j] = (_Float16)bf[j];
        }
        acc = __builtin_amdgcn_mfma_f32_16x16x32_f16(ah, bh, acc, 0, 0, 0);
        acc = __builtin_amdgcn_mfma_f32_16x16x32_f16(al, bh, acc, 0, 0, 0);
    }
#pragma unroll
    for (int r = 0; r < 4; r++) red[wave][lane][r] = acc[r];
    __syncthreads();
    if (wave == 0 && quad < 2) {                     // rows m = quad*4+r in [0,8)
        float bias = fcb[n];
#pragma unroll
        for (int r = 0; r < 4; r++) {
            float v = red[0][lane][r] + red[1][lane][r]
                    + red[2][lane][r] + red[3][lane][r];
            wout[(size_t)(quad * 4 + r) * NPAR + n] = v + bias;
        }
    }
}

// ---------------------------------------------------------------------------
// Stage 1.5: build frag-ready fp16 coef tensor (now used as the A operand;
// same lane algebra as before). bt[b*4608 + ks*256 + ln*4 + dq].
// ks: 0-1 L1, 2-9 L2, 10-17 L3. Slots rk<11 -> coef*uw, 11/12 -> rw,
// 13 -> rw_lo, 14/15 -> 0. (unchanged)
// ---------------------------------------------------------------------------
__global__ __launch_bounds__(256) void pack_b(const float* __restrict__ w,
                                              unsigned int* __restrict__ bt) {
    int idx = blockIdx.x * 256 + threadIdx.x;       // < 36864
    if (idx >= 8 * 4608) return;
    int b = idx / 4608, r = idx - b * 4608;
    int ks = r >> 8, ln = (r >> 2) & 63, dq = r & 3;
    int q = ln >> 4, n = ln & 15;
    int lay, s;
    if (ks < 2)       { lay = 0; s = ks; }
    else if (ks < 10) { lay = 1; s = ks - 2; }
    else              { lay = 2; s = ks - 10; }
    int i = 2 * s + (q >> 1);
    const float* wb = w + b * NPAR;
    int cb, ub, rb2, nd, ni;
    if (lay == 0)      { cb = 0;    ub = 528;  rb2 = 576;  nd = 16; ni = 3;  }
    else if (lay == 1) { cb = 624;  ub = 3440; rb2 = 3696; nd = 16; ni = 16; }
    else               { cb = 3952; ub = 4480; rb2 = 4528; nd = 3;  ni = 16; }
    unsigned int pk = 0;
    if (i < ni && n < nd) {
        float uwv = wb[ub + i * nd + n];
        float rwv = wb[rb2 + i * nd + n];
        unsigned short rh = f2h(rwv);
        float rl = rwv - h2f(rh);
#pragma unroll
        for (int h = 0; h < 2; h++) {
            int rk = (q & 1) * 8 + dq * 2 + h;
            float v = 0.f;
            if (rk < 11)       v = wb[cb + (i * nd + n) * 11 + rk] * uwv;
            else if (rk < 13)  v = rwv;
            else if (rk == 13) v = rl;
            pk |= ((unsigned int)f2h(v)) << (16 * h);
        }
    }
    bt[idx] = pk;
}

// ---------------------------------------------------------------------------
// Stage 2: KAN via fp16 MFMA, operand roles swapped: A = coef (m=output,
// from bt), B = pixel basis row composed IN REGISTERS (n = pixel).
// Wave handles 16 pixels. Thread (q,nn): pixel nn, channel c=2s+(q>>1),
// 8-slot window g=q&1. y handoff between layers via 2 __shfl from the
// previous layer's D-layout accs (lane (s>>1)*16+nn, regs static per s).
// NO LDS, NO barriers anywhere.
// ---------------------------------------------------------------------------
__global__ __launch_bounds__(256) void kan_mfma(const float* __restrict__ x,
                                                const unsigned int* __restrict__ bt,
                                                float* __restrict__ out) {
    const int tid  = threadIdx.x;
    const int lane = tid & 63, wv = tid >> 6;
    const int quad = lane >> 4, nn = lane & 15;
    const int g  = quad & 1;             // window within channel row
    const int hi = quad >> 1;            // which of the 2 channels this kstep
    const int g4 = g * 4;
    const int gtile = blockIdx.x * 4 + wv;          // 16-px tile, 0..25087
    const int b = gtile / 3136;
    const int px0 = (gtile - b * 3136) * 16;
    const unsigned int* btb = bt + b * 4608;

    const float* xb = x + (size_t)b * 3 * HW + px0 + nn;
    float xv0 = xb[0], xv1 = xb[HW], xv2 = xb[2 * HW];

    // Compose this thread's 4-dword B-frag window for basis row of y.
    // Proven R12 machinery, halved: taps (RTZ) via 3-dword window at
    // dword m=jt3>>1; statics OR'd into dwords 5,6 (window 1 only).
    auto composeB = [&](float y) -> int4v {
        float t  = (y + 1.75f) * 4.0f;
        float ft = floorf(t);
        ft = fminf(fmaxf(ft, -8.0f), 24.0f);
        float u = t - ft;
        u = fminf(fmaxf(u, -8.0f), 8.0f);
        float u2 = u * u, u3 = u2 * u, om = 1.0f - u;
        float b0 = (1.0f / 6.0f) * om * om * om;
        float b3 = (1.0f / 6.0f) * u3;
        float b1 = 0.5f * u3 - u2 + (2.0f / 3.0f);
        float b2 = 1.0f - b0 - b1 - b3;
        int jt3 = (int)ft - 3;
        float z0 = ((unsigned)jt3       <= 10u) ? b0 : 0.f;
        float z1 = ((unsigned)(jt3 + 1) <= 10u) ? b1 : 0.f;
        float z2 = ((unsigned)(jt3 + 2) <= 10u) ? b2 : 0.f;
        float z3 = ((unsigned)(jt3 + 3) <= 10u) ? b3 : 0.f;
        bool odd = (jt3 & 1) != 0;
        int I0 = pkrtz(odd ? 0.f : z0, odd ? z0 : z1);
        int I1 = pkrtz(odd ? z1 : z2, odd ? z2 : z3);
        int I2 = pkrtz(odd ? z3 : 0.f, 0.f);
        int mrel = (jt3 >> 1) - g4;
        int4v d;
#pragma unroll
        for (int k = 0; k < 4; k++) {
            int e = k - mrel;
            d[k] = (e == 0) ? I0 : (e == 1) ? I1 : (e == 2) ? I2 : 0;
        }
        float sil = y * __builtin_amdgcn_rcpf(1.0f + __expf(-y));
        unsigned short sh = f2h(sil);
        float sl = sil - h2f(sh);
        d[1] |= g ? (int)((unsigned int)sh << 16) : 0;   // slot 11 (tap part masked 0)
        d[2] |= g ? pkrtz(sl, sil) : 0;                  // slots 12,13 (tap part 0)
        return d;
    };

    auto kstep = [&](int ks, float y, f32x4& a) {
        union { half8 h; int4v v; } af, bf;
        af.v = *(const int4v*)(btb + ks * 256 + lane * 4);   // coef = A operand
        bf.v = composeB(y);
        a = __builtin_amdgcn_mfma_f32_16x16x32_f16(af.h, bf.h, a, 0, 0, 0);
    };

    // ================= Layer 1 (2 ksteps; ch3's A is zero) =================
    f32x4 a1 = {0.f, 0.f, 0.f, 0.f};
    kstep(0, hi ? xv1 : xv0, a1);
    kstep(1, xv2, a1);                   // hi=1 -> ch3: A==0, any finite B ok

    // ================= Layer 2 (8 ksteps) ==================================
    f32x4 a2 = {0.f, 0.f, 0.f, 0.f};
    {
        float p0 = a1[0], p1 = a1[1], p2 = a1[2], p3 = a1[3];
#pragma unroll
        for (int s = 0; s < 8; s++) {
            int srcl = (s >> 1) * 16 + nn;
            float yc0 = __shfl((s & 1) ? p2 : p0, srcl, 64);
            float yc1 = __shfl((s & 1) ? p3 : p1, srcl, 64);
            kstep(2 + s, hi ? yc1 : yc0, a2);
        }
    }

    // ================= Layer 3 (8 ksteps, N=3 used) ========================
    f32x4 a3 = {0.f, 0.f, 0.f, 0.f};
    {
        float p0 = a2[0], p1 = a2[1], p2 = a2[2], p3 = a2[3];
#pragma unroll
        for (int s = 0; s < 8; s++) {
            int srcl = (s >> 1) * 16 + nn;
            float yc0 = __shfl((s & 1) ? p2 : p0, srcl, 64);
            float yc1 = __shfl((s & 1) ? p3 : p1, srcl, 64);
            kstep(10 + s, hi ? yc1 : yc0, a3);
        }
    }

    // store: D[m=o][n=px]; rows o=0..2 live in quad 0, regs 0..2
    if (quad == 0) {
        float* ob = out + (size_t)b * 3 * HW + px0 + nn;
        ob[0]      = a3[0];
        ob[HW]     = a3[1];
        ob[2 * HW] = a3[2];
    }
}

// ---------------------------------------------------------------------------
extern "C" void kernel_launch(void* const* d_in, const int* in_sizes, int n_in,
                              void* d_out, int out_size, void* d_ws, size_t ws_size,
                              hipStream_t stream) {
    const float* x     = (const float*)d_in[0];   // (8,3,224,224)
    const float* feats = (const float*)d_in[1];   // (8,1000)
    const float* fcw   = (const float*)d_in[2];   // (4576,1000)
    const float* fcb   = (const float*)d_in[3];   // (4576,)
    float* outp = (float*)d_out;
    float* wbuf = (float*)d_ws;                               // 36608 floats
    unsigned int* btens = (unsigned int*)d_ws + 36608;        // 36864 dwords

    hipLaunchKernelGGL(gemm_w, dim3(286), dim3(256), 0, stream,
                       feats, fcw, fcb, wbuf);
    hipLaunchKernelGGL(pack_b, dim3(144), dim3(256), 0, stream,
                       wbuf, btens);
    hipLaunchKernelGGL(kan_mfma, dim3(6272), dim3(256), 0, stream,
                       x, btens, outp);
}

// Round 16
// 112.410 us; speedup vs baseline: 1.2844x; 1.2844x over previous
//
#include <hip/hip_runtime.h>

#define HW   50176      // 224*224
#define NPAR 4576       // KAN_PARAMS_NUM

typedef _Float16 half8 __attribute__((ext_vector_type(8)));
typedef __fp16 fp16x2 __attribute__((ext_vector_type(2)));
typedef __attribute__((ext_vector_type(4))) float f32x4;
typedef __attribute__((ext_vector_type(4))) int int4v;

__device__ __forceinline__ unsigned short f2h(float f) {
    union { _Float16 h; unsigned short u; } c; c.h = (_Float16)f; return c.u;
}
__device__ __forceinline__ float h2f(unsigned short u) {
    union { _Float16 h; unsigned short u; } c; c.u = u; return (float)c.h;
}

// ---------------------------------------------------------------------------
// Stage 1: w[m][n] = features[m][:] . fc_w[n][:] + fc_b[n]  via fp16 MFMA.
// Split-K across 4 waves + LDS reduction. 286 blocks (16 n each).
// ---------------------------------------------------------------------------
__global__ __launch_bounds__(256) void gemm_w(const float* __restrict__ feats,
                                              const float* __restrict__ fcw,
                                              const float* __restrict__ fcb,
                                              float* __restrict__ wout) {
    __shared__ float red[4][64][4];
    int tid = threadIdx.x, lane = tid & 63, wave = tid >> 6;
    int nn = lane & 15, quad = lane >> 4;
    int n = blockIdx.x * 16 + nn;
    const float* brow = fcw + (size_t)n * 1000;
    const float* arow = feats + nn * 1000;          // deref'd only if nn<8

    f32x4 acc = {0.f, 0.f, 0.f, 0.f};
#pragma unroll 4
    for (int s8 = 0; s8 < 8; s8++) {
        int kb = (wave * 8 + s8) * 32 + quad * 8;
        float4 a0 = {0,0,0,0}, a1 = {0,0,0,0}, b0 = {0,0,0,0}, b1 = {0,0,0,0};
        if (kb < 1000) {                            // 1000 % 8 == 0
            b0 = *(const float4*)(brow + kb);
            b1 = *(const float4*)(brow + kb + 4);
            if (nn < 8) {
                a0 = *(const float4*)(arow + kb);
                a1 = *(const float4*)(arow + kb + 4);
            }
        }
        float af[8] = {a0.x, a0.y, a0.z, a0.w, a1.x, a1.y, a1.z, a1.w};
        float bf[8] = {b0.x, b0.y, b0.z, b0.w, b1.x, b1.y, b1.z, b1.w};
        half8 ah, al, bh;
#pragma unroll
        for (int j = 0; j < 8; j++) {
            ah[j] = (_Float16)af[j];
            al[j] = (_Float16)(af[j] - (float)ah[j]);
            bh[j] = (_Float16)bf[j];
        }
        acc = __builtin_amdgcn_mfma_f32_16x16x32_f16(ah, bh, acc, 0, 0, 0);
        acc = __builtin_amdgcn_mfma_f32_16x16x32_f16(al, bh, acc, 0, 0, 0);
    }
#pragma unroll
    for (int r = 0; r < 4; r++) red[wave][lane][r] = acc[r];
    __syncthreads();
    if (wave == 0 && quad < 2) {                     // rows m = quad*4+r in [0,8)
        float bias = fcb[n];
#pragma unroll
        for (int r = 0; r < 4; r++) {
            float v = red[0][lane][r] + red[1][lane][r]
                    + red[2][lane][r] + red[3][lane][r];
            wout[(size_t)(quad * 4 + r) * NPAR + n] = v + bias;
        }
    }
}

// ---------------------------------------------------------------------------
// Stage 1.5: build frag-ready fp16 B tensor in ws.
// bt[b*4608 + ks*256 + ln*4 + dq], ks: 0-1 L1, 2-9 L2, 10-17 L3.
// Slots rk<11 -> coef*uw, 11/12 -> rw, 13 -> rw_lo, 14/15 -> 0.
// ---------------------------------------------------------------------------
__global__ __launch_bounds__(256) void pack_b(const float* __restrict__ w,
                                              unsigned int* __restrict__ bt) {
    int idx = blockIdx.x * 256 + threadIdx.x;       // < 36864
    if (idx >= 8 * 4608) return;
    int b = idx / 4608, r = idx - b * 4608;
    int ks = r >> 8, ln = (r >> 2) & 63, dq = r & 3;
    int q = ln >> 4, n = ln & 15;
    int lay, s;
    if (ks < 2)       { lay = 0; s = ks; }
    else if (ks < 10) { lay = 1; s = ks - 2; }
    else              { lay = 2; s = ks - 10; }
    int i = 2 * s + (q >> 1);
    const float* wb = w + b * NPAR;
    int cb, ub, rb2, nd, ni;
    if (lay == 0)      { cb = 0;    ub = 528;  rb2 = 576;  nd = 16; ni = 3;  }
    else if (lay == 1) { cb = 624;  ub = 3440; rb2 = 3696; nd = 16; ni = 16; }
    else               { cb = 3952; ub = 4480; rb2 = 4528; nd = 3;  ni = 16; }
    unsigned int pk = 0;
    if (i < ni && n < nd) {
        float uwv = wb[ub + i * nd + n];
        float rwv = wb[rb2 + i * nd + n];
        unsigned short rh = f2h(rwv);
        float rl = rwv - h2f(rh);
#pragma unroll
        for (int h = 0; h < 2; h++) {
            int rk = (q & 1) * 8 + dq * 2 + h;
            float v = 0.f;
            if (rk < 11)       v = wb[cb + (i * nd + n) * 11 + rk] * uwv;
            else if (rk < 13)  v = rwv;
            else if (rk == 13) v = rl;
            pk |= ((unsigned int)f2h(v)) << (16 * h);
        }
    }
    bt[idx] = pk;
}

// ---------------------------------------------------------------------------
// Scatter one channel-row (16 fp16 slots = 8 dwords, 16B-aligned base).
// Store order (R8/R11-proven): full image via two b128 stores (zeros +
// statics), THEN taps as shorts; dead taps go ONLY to slot 15 (B=0 there).
//   slots 0-10: cubic taps at jt-3..jt; slot 11 = sil_hi, 12 = sil_lo,
//   13 = sil_hi(rtz), 14/15 = 0.
// ---------------------------------------------------------------------------
__device__ __forceinline__ void scatter_row(int* rowp, float y) {
    float t  = (y + 1.75f) * 4.0f;
    float ft = floorf(t);
    ft = fminf(fmaxf(ft, -8.0f), 24.0f);
    float u = t - ft;
    u = fminf(fmaxf(u, -8.0f), 8.0f);
    float u2 = u * u, u3 = u2 * u, om = 1.0f - u;
    float b0 = (1.0f / 6.0f) * om * om * om;
    float b3 = (1.0f / 6.0f) * u3;
    float b1 = 0.5f * u3 - u2 + (2.0f / 3.0f);
    float b2 = 1.0f - b0 - b1 - b3;
    float sil = y * __builtin_amdgcn_rcpf(1.0f + __expf(-y));

    unsigned short sh = f2h(sil);
    float sl = sil - h2f(sh);
    union { fp16x2 h; int i; } pk;
    pk.h = __builtin_amdgcn_cvt_pkrtz(sl, sil);  // lo=sil_lo, hi=sil_rtz

    int4v z = {0, 0, 0, 0};
    int4v w1;
    w1[0] = 0;                                   // slots 8,9
    w1[1] = (int)((unsigned int)sh << 16);       // slots 10(=0),11
    w1[2] = pk.i;                                // slots 12,13
    w1[3] = 0;                                   // slots 14,15
    *(int4v*)rowp = z;                           // slots 0-7
    *(int4v*)(rowp + 4) = w1;                    // slots 8-15

    int jt3 = (int)ft - 3;
    short* sp = (short*)rowp;
    unsigned short hb[4] = {f2h(b0), f2h(b1), f2h(b2), f2h(b3)};
#pragma unroll
    for (int j = 0; j < 4; j++) {
        int s = jt3 + j;
        int slot = ((unsigned)s <= 10u) ? s : 15;   // dead -> slot 15 (B=0)
        sp[slot] = (short)hb[j];
    }
}

// Per-wave LDS region: 1280 dwords. A-view: 64 rows x stride 20 (dw0-15
// content; 16B-aligned, bank-balanced b128). y-view (OVERLAID, temporally
// disjoint): 64 px x stride 18. 2 waves/block.
#define ASTR  20
#define YSTR  18
#define WREG  1280

// ---------------------------------------------------------------------------
// Stage 2: KAN via fp16 MFMA. Block = 2 independent waves; wave owns 64 px
// (784 tiles per batch). Per-layer B-frag preload + fully unrolled ksteps.
// ---------------------------------------------------------------------------
__global__ __launch_bounds__(128) void kan_mfma(const float* __restrict__ x,
                                                const unsigned int* __restrict__ bt,
                                                float* __restrict__ out) {
    __shared__ __align__(16) int lds[2 * WREG];
    const int tid  = threadIdx.x;
    const int lane = tid & 63, wv = tid >> 6;
    const int quad = lane >> 4, nn = lane & 15;
    const int gtile = blockIdx.x * 2 + wv;           // 64-px tile, 0..6271
    const int b = gtile / 784;                       // 784 tiles per batch
    const int px0 = (gtile - b * 784) * 64;
    const unsigned int* btb = bt + b * 4608 + lane * 4;
    const int wbase = wv * WREG;
    float* ybf = (float*)&lds[wbase];                // overlaid y-view

    int* rowE = &lds[wbase + ASTR * lane];           // even-channel row
    int* rowO = rowE + 8;                            // odd-channel row
    const int aob = wbase + ASTR * nn + 4 * quad;

    const float* xg = x + (size_t)b * 3 * HW + px0 + lane;
    float xv0 = xg[0], xv1 = xg[HW], xv2 = xg[2 * HW];

    f32x4 acc[4];

    auto mfma4 = [&](int4v bv) {
        union { half8 h; int4v v; } bf;
        bf.v = bv;
        asm volatile("s_waitcnt lgkmcnt(0)" ::: "memory");
#pragma unroll
        for (int mt = 0; mt < 4; mt++) {
            union { half8 h; int4v v; } af;
            af.v = *(int4v*)&lds[aob + mt * (16 * ASTR)];
            acc[mt] = __builtin_amdgcn_mfma_f32_16x16x32_f16(af.h, bf.h, acc[mt], 0, 0, 0);
        }
    };

    // ================= Layer 1 (K=48 -> 2 ksteps; ch3's B is zero) =========
    {
        int4v b0v = *(const int4v*)(btb + 0 * 256);
        int4v b1v = *(const int4v*)(btb + 1 * 256);
#pragma unroll
        for (int mt = 0; mt < 4; mt++) acc[mt] = (f32x4){0.f, 0.f, 0.f, 0.f};
        scatter_row(rowE, xv0);
        scatter_row(rowO, xv1);
        mfma4(b0v);
        asm volatile("" ::: "memory");
        scatter_row(rowE, xv2);          // odd row stale (ch1) but B==0 there
        mfma4(b1v);
    }
    // write y1 into overlay (A-rows dead: last reads drained pre-MFMA)
#pragma unroll
    for (int mt = 0; mt < 4; mt++)
#pragma unroll
        for (int r = 0; r < 4; r++)
            ybf[(mt * 16 + quad * 4 + r) * YSTR + nn] = acc[mt][r];
    asm volatile("s_waitcnt lgkmcnt(0)" ::: "memory");

    // ================= Layer 2 (K=256 -> 8 ksteps) =========================
    {
        int4v bfr[8];
#pragma unroll
        for (int s = 0; s < 8; s++)
            bfr[s] = *(const int4v*)(btb + (2 + s) * 256);
        float yv[16];
#pragma unroll
        for (int j = 0; j < 8; j++) {
            float2 p = *(const float2*)&ybf[lane * YSTR + 2 * j];
            yv[2 * j] = p.x; yv[2 * j + 1] = p.y;
        }
        asm volatile("s_waitcnt lgkmcnt(0)" ::: "memory");  // y reads done before A overwrites
#pragma unroll
        for (int mt = 0; mt < 4; mt++) acc[mt] = (f32x4){0.f, 0.f, 0.f, 0.f};
#pragma unroll
        for (int s = 0; s < 8; s++) {
            asm volatile("" ::: "memory");
            scatter_row(rowE, yv[2 * s]);
            scatter_row(rowO, yv[2 * s + 1]);
            mfma4(bfr[s]);
        }
    }
#pragma unroll
    for (int mt = 0; mt < 4; mt++)
#pragma unroll
        for (int r = 0; r < 4; r++)
            ybf[(mt * 16 + quad * 4 + r) * YSTR + nn] = acc[mt][r];
    asm volatile("s_waitcnt lgkmcnt(0)" ::: "memory");

    // ================= Layer 3 (K=256 -> 8 ksteps, N=3 used) ===============
    {
        int4v bfr[8];
#pragma unroll
        for (int s = 0; s < 8; s++)
            bfr[s] = *(const int4v*)(btb + (10 + s) * 256);
        float yv[16];
#pragma unroll
        for (int j = 0; j < 8; j++) {
            float2 p = *(const float2*)&ybf[lane * YSTR + 2 * j];
            yv[2 * j] = p.x; yv[2 * j + 1] = p.y;
        }
        asm volatile("s_waitcnt lgkmcnt(0)" ::: "memory");
#pragma unroll
        for (int mt = 0; mt < 4; mt++) acc[mt] = (f32x4){0.f, 0.f, 0.f, 0.f};
#pragma unroll
        for (int s = 0; s < 8; s++) {
            asm volatile("" ::: "memory");
            scatter_row(rowE, yv[2 * s]);
            scatter_row(rowO, yv[2 * s + 1]);
            mfma4(bfr[s]);
        }
    }

    // transpose D through overlay for coalesced stores
    if (nn < 3) {
#pragma unroll
        for (int mt = 0; mt < 4; mt++)
#pragma unroll
            for (int r = 0; r < 4; r++)
                ybf[(mt * 16 + quad * 4 + r) * YSTR + nn] = acc[mt][r];
    }
    asm volatile("s_waitcnt lgkmcnt(0)" ::: "memory");
    float c0 = ybf[lane * YSTR + 0];
    float c1 = ybf[lane * YSTR + 1];
    float c2 = ybf[lane * YSTR + 2];
    float* ob = out + (size_t)b * 3 * HW + px0 + lane;
    ob[0]      = c0;
    ob[HW]     = c1;
    ob[2 * HW] = c2;
}

// ---------------------------------------------------------------------------
extern "C" void kernel_launch(void* const* d_in, const int* in_sizes, int n_in,
                              void* d_out, int out_size, void* d_ws, size_t ws_size,
                              hipStream_t stream) {
    const float* x     = (const float*)d_in[0];   // (8,3,224,224)
    const float* feats = (const float*)d_in[1];   // (8,1000)
    const float* fcw   = (const float*)d_in[2];   // (4576,1000)
    const float* fcb   = (const float*)d_in[3];   // (4576,)
    float* outp = (float*)d_out;
    float* wbuf = (float*)d_ws;                               // 36608 floats
    unsigned int* btens = (unsigned int*)d_ws + 36608;        // 36864 dwords

    hipLaunchKernelGGL(gemm_w, dim3(286), dim3(256), 0, stream,
                       feats, fcw, fcb, wbuf);
    hipLaunchKernelGGL(pack_b, dim3(144), dim3(256), 0, stream,
                       wbuf, btens);
    hipLaunchKernelGGL(kan_mfma, dim3(8 * 784 / 2), dim3(128), 0, stream,
                       x, btens, outp);
}